// Round 4
// baseline (1020.544 us; speedup 1.0000x reference)
//
#include <hip/hip_runtime.h>
#include <hip/hip_bf16.h>

// Problem constants
#define NB 16
#define DD 64
#define HW 4096          // 64*64
#define NTOT 65536       // NB*HW
#define KC 1024

// Output chunk offsets (FLOAT32 elements, return order)
#define O_EK   0                         // e_k_ste [16,64,64,64] = 4194304
#define O_IDX  4194304                   // indices [16,64,64]    = 65536
#define O_L    4259840                   // L_commit scalar       = 1
#define O_CB   4259841                   // new_codebook [1024,64]= 65536
#define O_CNT  4325377                   // new_count [1024]      = 1024
#define O_SUM  4326401                   // new_sum [1024,64]     = 65536

// Workspace layout (float element offsets) — total 67586 floats = 270,344 bytes
#define WS_COUNTS 0          // [0, 1024)
#define WS_SUMS   1024       // [1024, 66560)
#define WS_LC     66560
#define WS_N      66561
#define WS_CNORM  66562      // [66562, 67586)
#define WS_ZERO_LEN 66561    // counts + sums + lc

__global__ __launch_bounds__(256) void k_zero(float* __restrict__ p) {
    int i = blockIdx.x * 256 + threadIdx.x;
    if (i < WS_ZERO_LEN) p[i] = 0.0f;
}

__global__ __launch_bounds__(64) void k_cnorm(const float* __restrict__ cb,
                                              float* __restrict__ cnorm) {
    int k = blockIdx.x * 64 + threadIdx.x;
    const float* c = cb + (size_t)k * DD;
    float s = 0.f;
#pragma unroll 8
    for (int j = 0; j < DD; ++j) s = fmaf(c[j], c[j], s);
    cnorm[k] = s;
}

// Fused: distance GEMM + argmin + e_k_ste/index writes + counts/sums/L_commit.
// Block: 256 threads, tile 128 z-rows x all 1024 codes (16 tiles of 64).
__global__ __launch_bounds__(256) void k_main(const float* __restrict__ z_e,
                                              const float* __restrict__ cb,
                                              const float* __restrict__ cnorm,
                                              float* __restrict__ out,
                                              float* __restrict__ counts_ws,
                                              float* __restrict__ sums_ws,
                                              float* __restrict__ lc_ws) {
    __shared__ __align__(16) float At[64 * 128];   // z tile [j][i], live whole kernel
    __shared__ __align__(16) float Bt[64 * 68];    // codebook tile [j][k]; reused as reduce scratch
    __shared__ float zn[128];
    __shared__ int   idx_lds[128];

    const int t  = threadIdx.x;
    const int tx = t & 15;
    const int ty = t >> 4;
    const int n0 = blockIdx.x * 128;       // 512 blocks
    const int b   = n0 >> 12;
    const int hw0 = n0 & 4095;
    const float* zbase = z_e + (size_t)b * (DD * HW) + hw0;

    // ---- Load A tile (coalesced along hw) ----
#pragma unroll
    for (int s = 0; s < 8; ++s) {
        int idx = t + s * 256;              // 0..2047 float4s
        int j   = idx >> 5;
        int i4  = (idx & 31) << 2;
        float4 v = *(const float4*)(zbase + (size_t)j * HW + i4);
        *(float4*)(&At[j * 128 + i4]) = v;
    }
    __syncthreads();

    if (t < 128) {
        float s = 0.f;
        for (int j = 0; j < 64; ++j) { float a = At[j * 128 + t]; s = fmaf(a, a, s); }
        zn[t] = s;
    }
    __syncthreads();

    const int row0 = ty * 8, col0 = tx * 4;
    float znr[8];
#pragma unroll
    for (int r = 0; r < 8; ++r) znr[r] = zn[row0 + r];

    float mv[8]; int mi[8];
#pragma unroll
    for (int r = 0; r < 8; ++r) { mv[r] = 3.4e38f; mi[r] = 0; }

    for (int kt = 0; kt < 16; ++kt) {
        const int k0 = kt * 64;
        __syncthreads();                    // protect Bt from previous readers
#pragma unroll
        for (int s = 0; s < 4; ++s) {
            int idx = t + s * 256;          // 0..1023 float4s
            int kk  = idx >> 4;
            int j4  = (idx & 15) << 2;
            float4 v = *(const float4*)(cb + (size_t)(k0 + kk) * DD + j4);
            Bt[(j4 + 0) * 68 + kk] = v.x;
            Bt[(j4 + 1) * 68 + kk] = v.y;
            Bt[(j4 + 2) * 68 + kk] = v.z;
            Bt[(j4 + 3) * 68 + kk] = v.w;
        }
        __syncthreads();

        float acc[8][4];
#pragma unroll
        for (int r = 0; r < 8; ++r)
#pragma unroll
            for (int c = 0; c < 4; ++c) acc[r][c] = 0.f;

#pragma unroll 8
        for (int j = 0; j < 64; ++j) {
            float4 a0 = *(const float4*)(&At[j * 128 + row0]);
            float4 a1 = *(const float4*)(&At[j * 128 + row0 + 4]);
            float4 bq = *(const float4*)(&Bt[j * 68 + col0]);
            float ar[8] = {a0.x, a0.y, a0.z, a0.w, a1.x, a1.y, a1.z, a1.w};
            float bc[4] = {bq.x, bq.y, bq.z, bq.w};
#pragma unroll
            for (int r = 0; r < 8; ++r)
#pragma unroll
                for (int c = 0; c < 4; ++c)
                    acc[r][c] = fmaf(ar[r], bc[c], acc[r][c]);
        }

#pragma unroll
        for (int c = 0; c < 4; ++c) {
            float cn = cnorm[k0 + col0 + c];
            int   kg = k0 + col0 + c;
#pragma unroll
            for (int r = 0; r < 8; ++r) {
                float v = (znr[r] - 2.0f * acc[r][c]) + cn;
                if (v < mv[r]) { mv[r] = v; mi[r] = kg; }   // kg ascending -> first-min
            }
        }
    }

    // ---- Argmin reduction in Bt scratch (At stays intact) ----
    __syncthreads();
    float* rv = Bt;                       // [128][17] floats = 2176
    int*   ri = (int*)(Bt + 2176);        // [128][17] ints   = 2176 (total 4352 = |Bt|)
#pragma unroll
    for (int r = 0; r < 8; ++r) {
        rv[(row0 + r) * 17 + tx] = mv[r];
        ri[(row0 + r) * 17 + tx] = mi[r];
    }
    __syncthreads();
    if (t < 128) {
        float best = rv[t * 17 + 0];
        int   bi   = ri[t * 17 + 0];
#pragma unroll
        for (int c = 1; c < 16; ++c) {
            float v = rv[t * 17 + c];
            int   i = ri[t * 17 + c];
            if (v < best || (v == best && i < bi)) { best = v; bi = i; }
        }
        if ((unsigned)bi > 1023u) bi = 0;
        idx_lds[t] = bi;
        out[O_IDX + n0 + t] = (float)bi;    // fp32 index value
    }
    __syncthreads();

    // ---- Scatter phase: rows r = t>>1, j-halves by t&1; z comes from At (LDS) ----
    const int r   = t >> 1;
    const int j0  = (t & 1) * 32;
    int k = idx_lds[r];
    if ((unsigned)k > 1023u) k = 0;
    const float* ck = cb + (size_t)k * DD;
    float* sk = sums_ws + (size_t)k * DD;
    const size_t obase = (size_t)b * (DD * HW) + (size_t)(hw0 + r);

    float lc = 0.f;
#pragma unroll 8
    for (int j = j0; j < j0 + 32; ++j) {
        float z = At[j * 128 + r];
        float e = ck[j];
        out[O_EK + obase + (size_t)j * HW] = z + (e - z);   // STE forward value
        float d = z - e;
        lc = fmaf(d, d, lc);
        atomicAdd(&sk[j], z);
    }
    if ((t & 1) == 0) atomicAdd(&counts_ws[k], 1.0f);

#pragma unroll
    for (int m = 32; m >= 1; m >>= 1) lc += __shfl_xor(lc, m, 64);
    if ((t & 63) == 0) atomicAdd(lc_ws, lc);
}

__global__ __launch_bounds__(1024) void k_final_count(const float* __restrict__ ema_count,
                                                      const float* __restrict__ counts_ws,
                                                      const float* __restrict__ lc_ws,
                                                      float* __restrict__ out,
                                                      float* __restrict__ n_ws) {
    __shared__ float red[1024];
    const int k = threadIdx.x;
    float nc = ema_count[k] * 0.99f + 0.01f * counts_ws[k];
    out[O_CNT + k] = nc;
    red[k] = nc;
    __syncthreads();
    for (int s = 512; s >= 1; s >>= 1) {
        if (k < s) red[k] += red[k + s];
        __syncthreads();
    }
    if (k == 0) {
        n_ws[0] = red[0];
        out[O_L] = 1.25f * lc_ws[0] * (1.0f / 4194304.0f);
    }
}

__global__ __launch_bounds__(256) void k_final_sum(const float* __restrict__ ema_sum,
                                                   const float* __restrict__ ema_count,
                                                   const float* __restrict__ sums_ws,
                                                   const float* __restrict__ counts_ws,
                                                   const float* __restrict__ n_ws,
                                                   float* __restrict__ out) {
    const int e = blockIdx.x * 256 + threadIdx.x;   // 0..65535
    const int k = e >> 6;
    float ns = ema_sum[e] * 0.99f + 0.01f * sums_ws[e];
    out[O_SUM + e] = ns;
    float nc = ema_count[k] * 0.99f + 0.01f * counts_ws[k];
    float n  = n_ws[0];
    float cs = (nc + 1e-5f) / (n + 1024.0f * 1e-5f) * n;
    out[O_CB + e] = ns / cs;
}

extern "C" void kernel_launch(void* const* d_in, const int* in_sizes, int n_in,
                              void* d_out, int out_size, void* d_ws, size_t ws_size,
                              hipStream_t stream) {
    const float* z_e       = (const float*)d_in[0];
    const float* cb        = (const float*)d_in[1];
    const float* ema_count = (const float*)d_in[2];
    const float* ema_sum   = (const float*)d_in[3];
    float* out             = (float*)d_out;

    float* ws_f      = (float*)d_ws;
    float* counts_ws = ws_f + WS_COUNTS;
    float* sums_ws   = ws_f + WS_SUMS;
    float* lc_ws     = ws_f + WS_LC;
    float* n_ws      = ws_f + WS_N;
    float* cnorm_ws  = ws_f + WS_CNORM;

    k_zero<<<(WS_ZERO_LEN + 255) / 256, 256, 0, stream>>>(ws_f);
    k_cnorm<<<KC / 64, 64, 0, stream>>>(cb, cnorm_ws);
    k_main<<<NTOT / 128, 256, 0, stream>>>(z_e, cb, cnorm_ws, out, counts_ws, sums_ws, lc_ws);
    k_final_count<<<1, 1024, 0, stream>>>(ema_count, counts_ws, lc_ws, out, n_ws);
    k_final_sum<<<NTOT / 256, 256, 0, stream>>>(ema_sum, ema_count, sums_ws, counts_ws, n_ws, out);
}

// Round 5
// 366.661 us; speedup vs baseline: 2.7833x; 2.7833x over previous
//
#include <hip/hip_runtime.h>
#include <hip/hip_bf16.h>

// Problem constants
#define NB 16
#define DD 64
#define HW 4096          // 64*64
#define NTOT 65536       // NB*HW
#define KC 1024

// Output chunk offsets (FLOAT32 elements, return order)
#define O_EK   0                         // e_k_ste [16,64,64,64] = 4194304
#define O_IDX  4194304                   // indices [16,64,64]    = 65536
#define O_L    4259840                   // L_commit scalar       = 1
#define O_CB   4259841                   // new_codebook [1024,64]= 65536
#define O_CNT  4325377                   // new_count [1024]      = 1024
#define O_SUM  4326401                   // new_sum [1024,64]     = 65536

// Workspace layout (float/int element offsets) — total ~272 KB, nothing pre-zeroed
#define WS_IDX    0          // [0, 65536) int32
#define WS_LCPART 65536      // [65536, 66048) 512 floats
#define WS_COUNTS 66048      // [66048, 67072) new_count values (fp32)
#define WS_CNORM  67072      // [67072, 68096)
#define WS_N      68096      // scalar

__global__ __launch_bounds__(64) void k_cnorm(const float* __restrict__ cb,
                                              float* __restrict__ cnorm) {
    int k = blockIdx.x * 64 + threadIdx.x;
    const float* c = cb + (size_t)k * DD;
    float s = 0.f;
#pragma unroll 8
    for (int j = 0; j < DD; ++j) s = fmaf(c[j], c[j], s);
    cnorm[k] = s;
}

// Fused: distance GEMM + argmin + e_k_ste/index writes + L_commit partial.
// Block: 256 threads, tile 128 z-rows x all 1024 codes (16 tiles of 64). NO global atomics.
__global__ __launch_bounds__(256) void k_main(const float* __restrict__ z_e,
                                              const float* __restrict__ cb,
                                              const float* __restrict__ cnorm,
                                              float* __restrict__ out,
                                              int* __restrict__ idx_ws,
                                              float* __restrict__ lc_part) {
    __shared__ __align__(16) float At[64 * 128];   // z tile [j][i], live whole kernel
    __shared__ __align__(16) float Bt[64 * 68];    // codebook tile [j][k]; reused as reduce scratch
    __shared__ float zn[128];
    __shared__ int   idx_lds[128];
    __shared__ float lcred[4];

    const int t  = threadIdx.x;
    const int tx = t & 15;
    const int ty = t >> 4;
    const int n0 = blockIdx.x * 128;       // 512 blocks
    const int b   = n0 >> 12;
    const int hw0 = n0 & 4095;
    const float* zbase = z_e + (size_t)b * (DD * HW) + hw0;

    // ---- Load A tile (coalesced along hw) ----
#pragma unroll
    for (int s = 0; s < 8; ++s) {
        int idx = t + s * 256;              // 0..2047 float4s
        int j   = idx >> 5;
        int i4  = (idx & 31) << 2;
        float4 v = *(const float4*)(zbase + (size_t)j * HW + i4);
        *(float4*)(&At[j * 128 + i4]) = v;
    }
    __syncthreads();

    if (t < 128) {
        float s = 0.f;
        for (int j = 0; j < 64; ++j) { float a = At[j * 128 + t]; s = fmaf(a, a, s); }
        zn[t] = s;
    }
    __syncthreads();

    const int row0 = ty * 8, col0 = tx * 4;
    float znr[8];
#pragma unroll
    for (int r = 0; r < 8; ++r) znr[r] = zn[row0 + r];

    float mv[8]; int mi[8];
#pragma unroll
    for (int r = 0; r < 8; ++r) { mv[r] = 3.4e38f; mi[r] = 0; }

    for (int kt = 0; kt < 16; ++kt) {
        const int k0 = kt * 64;
        __syncthreads();                    // protect Bt from previous readers
#pragma unroll
        for (int s = 0; s < 4; ++s) {
            int idx = t + s * 256;          // 0..1023 float4s
            int kk  = idx >> 4;
            int j4  = (idx & 15) << 2;
            float4 v = *(const float4*)(cb + (size_t)(k0 + kk) * DD + j4);
            Bt[(j4 + 0) * 68 + kk] = v.x;
            Bt[(j4 + 1) * 68 + kk] = v.y;
            Bt[(j4 + 2) * 68 + kk] = v.z;
            Bt[(j4 + 3) * 68 + kk] = v.w;
        }
        __syncthreads();

        float acc[8][4];
#pragma unroll
        for (int r = 0; r < 8; ++r)
#pragma unroll
            for (int c = 0; c < 4; ++c) acc[r][c] = 0.f;

#pragma unroll 8
        for (int j = 0; j < 64; ++j) {
            float4 a0 = *(const float4*)(&At[j * 128 + row0]);
            float4 a1 = *(const float4*)(&At[j * 128 + row0 + 4]);
            float4 bq = *(const float4*)(&Bt[j * 68 + col0]);
            float ar[8] = {a0.x, a0.y, a0.z, a0.w, a1.x, a1.y, a1.z, a1.w};
            float bc[4] = {bq.x, bq.y, bq.z, bq.w};
#pragma unroll
            for (int r = 0; r < 8; ++r)
#pragma unroll
                for (int c = 0; c < 4; ++c)
                    acc[r][c] = fmaf(ar[r], bc[c], acc[r][c]);
        }

#pragma unroll
        for (int c = 0; c < 4; ++c) {
            float cn = cnorm[k0 + col0 + c];
            int   kg = k0 + col0 + c;
#pragma unroll
            for (int r = 0; r < 8; ++r) {
                float v = (znr[r] - 2.0f * acc[r][c]) + cn;
                if (v < mv[r]) { mv[r] = v; mi[r] = kg; }   // kg ascending -> first-min
            }
        }
    }

    // ---- Argmin reduction in Bt scratch (At stays intact) ----
    __syncthreads();
    float* rv = Bt;                       // [128][17] floats = 2176
    int*   ri = (int*)(Bt + 2176);        // [128][17] ints   = 2176 (total 4352 = |Bt|)
#pragma unroll
    for (int r = 0; r < 8; ++r) {
        rv[(row0 + r) * 17 + tx] = mv[r];
        ri[(row0 + r) * 17 + tx] = mi[r];
    }
    __syncthreads();
    if (t < 128) {
        float best = rv[t * 17 + 0];
        int   bi   = ri[t * 17 + 0];
#pragma unroll
        for (int c = 1; c < 16; ++c) {
            float v = rv[t * 17 + c];
            int   i = ri[t * 17 + c];
            if (v < best || (v == best && i < bi)) { best = v; bi = i; }
        }
        if ((unsigned)bi > 1023u) bi = 0;
        idx_lds[t] = bi;
        out[O_IDX + n0 + t] = (float)bi;    // fp32 index value
        idx_ws[n0 + t] = bi;                // int copy for k_hist
    }
    __syncthreads();

    // ---- Scatter phase: rows r = t>>1, j-halves by t&1; z comes from At (LDS) ----
    const int r   = t >> 1;
    const int j0  = (t & 1) * 32;
    int k = idx_lds[r];
    const float* ck = cb + (size_t)k * DD;
    const size_t obase = (size_t)b * (DD * HW) + (size_t)(hw0 + r);

    float lc = 0.f;
#pragma unroll 8
    for (int j = j0; j < j0 + 32; ++j) {
        float z = At[j * 128 + r];
        float e = ck[j];
        out[O_EK + obase + (size_t)j * HW] = z + (e - z);   // STE forward value
        float d = z - e;
        lc = fmaf(d, d, lc);
    }
    // wave reduce, then block reduce via tiny LDS — no global atomics
#pragma unroll
    for (int m = 32; m >= 1; m >>= 1) lc += __shfl_xor(lc, m, 64);
    if ((t & 63) == 0) lcred[t >> 6] = lc;
    __syncthreads();
    if (t == 0) lc_part[blockIdx.x] = lcred[0] + lcred[1] + lcred[2] + lcred[3];
}

// One block per code k: scan indices, gather matching z rows, write new_sum/new_count.
#define CHUNK 8192
__global__ __launch_bounds__(256) void k_hist(const int* __restrict__ idx_ws,
                                              const float* __restrict__ z_e,
                                              const float* __restrict__ ema_count,
                                              const float* __restrict__ ema_sum,
                                              float* __restrict__ out,
                                              float* __restrict__ counts_ws) {
    __shared__ int list[CHUNK];
    __shared__ int cnt;
    __shared__ float red[256];
    const int k = blockIdx.x;          // 1024 blocks
    const int t = threadIdx.x;
    const int j = t & 63, slot = t >> 6;

    float acc = 0.f;
    int total = 0;
    for (int c = 0; c < NTOT; c += CHUNK) {
        __syncthreads();               // protect list from previous chunk's readers
        if (t == 0) cnt = 0;
        __syncthreads();
        for (int i = t; i < CHUNK; i += 256) {
            if (idx_ws[c + i] == k) { int p = atomicAdd(&cnt, 1); list[p] = c + i; }
        }
        __syncthreads();
        int m = cnt;
        total += m;
        for (int r = slot; r < m; r += 4) {
            int n = list[r];
            int b = n >> 12, hw = n & 4095;
            acc += z_e[(size_t)b * (DD * HW) + (size_t)j * HW + hw];
        }
    }
    red[t] = acc;
    __syncthreads();
    if (t < 64) {
        float s = red[t] + red[64 + t] + red[128 + t] + red[192 + t];
        float ns = ema_sum[(size_t)k * 64 + t] * 0.99f + 0.01f * s;
        out[O_SUM + (size_t)k * 64 + t] = ns;
    }
    if (t == 0) {
        float nc = ema_count[k] * 0.99f + 0.01f * (float)total;
        out[O_CNT + k] = nc;
        counts_ws[k] = nc;
    }
}

// n = sum(new_count); L_commit = 1.25 * sum(lc_part) / (B*d*h*w)
__global__ __launch_bounds__(1024) void k_final_nl(const float* __restrict__ counts_ws,
                                                   const float* __restrict__ lc_part,
                                                   float* __restrict__ out,
                                                   float* __restrict__ n_ws) {
    __shared__ float red[1024];
    const int t = threadIdx.x;
    red[t] = counts_ws[t];
    __syncthreads();
    for (int s = 512; s >= 1; s >>= 1) {
        if (t < s) red[t] += red[t + s];
        __syncthreads();
    }
    if (t == 0) n_ws[0] = red[0];
    __syncthreads();
    red[t] = (t < 512) ? lc_part[t] : 0.f;
    __syncthreads();
    for (int s = 512; s >= 1; s >>= 1) {
        if (t < s) red[t] += red[t + s];
        __syncthreads();
    }
    if (t == 0) out[O_L] = 1.25f * red[0] * (1.0f / 4194304.0f);
}

// new_codebook = new_sum / count_s  (reads new_sum back from out)
__global__ __launch_bounds__(256) void k_final_cb(const float* __restrict__ counts_ws,
                                                  const float* __restrict__ n_ws,
                                                  float* __restrict__ out) {
    const int e = blockIdx.x * 256 + threadIdx.x;   // 0..65535
    const int k = e >> 6;
    float ns = out[O_SUM + e];
    float nc = counts_ws[k];
    float n  = n_ws[0];
    float cs = (nc + 1e-5f) / (n + 1024.0f * 1e-5f) * n;
    out[O_CB + e] = ns / cs;
}

extern "C" void kernel_launch(void* const* d_in, const int* in_sizes, int n_in,
                              void* d_out, int out_size, void* d_ws, size_t ws_size,
                              hipStream_t stream) {
    const float* z_e       = (const float*)d_in[0];
    const float* cb        = (const float*)d_in[1];
    const float* ema_count = (const float*)d_in[2];
    const float* ema_sum   = (const float*)d_in[3];
    float* out             = (float*)d_out;

    float* ws_f      = (float*)d_ws;
    int*   idx_ws    = (int*)d_ws;                 // [0, 65536)
    float* lc_part   = ws_f + WS_LCPART;
    float* counts_ws = ws_f + WS_COUNTS;
    float* cnorm_ws  = ws_f + WS_CNORM;
    float* n_ws      = ws_f + WS_N;

    k_cnorm<<<KC / 64, 64, 0, stream>>>(cb, cnorm_ws);
    k_main<<<NTOT / 128, 256, 0, stream>>>(z_e, cb, cnorm_ws, out, idx_ws, lc_part);
    k_hist<<<KC, 256, 0, stream>>>(idx_ws, z_e, ema_count, ema_sum, out, counts_ws);
    k_final_nl<<<1, 1024, 0, stream>>>(counts_ws, lc_part, out, n_ws);
    k_final_cb<<<NTOT / 256, 256, 0, stream>>>(counts_ws, n_ws, out);
}

// Round 6
// 304.151 us; speedup vs baseline: 3.3554x; 1.2055x over previous
//
#include <hip/hip_runtime.h>
#include <hip/hip_bf16.h>

// Problem constants
#define NB 16
#define DD 64
#define HW 4096          // 64*64
#define NTOT 65536       // NB*HW
#define KC 1024

// Output chunk offsets (FLOAT32 elements, return order)
#define O_EK   0                         // e_k_ste [16,64,64,64] = 4194304
#define O_IDX  4194304                   // indices [16,64,64]    = 65536
#define O_L    4259840                   // L_commit scalar       = 1
#define O_CB   4259841                   // new_codebook [1024,64]= 65536
#define O_CNT  4325377                   // new_count [1024]      = 1024
#define O_SUM  4326401                   // new_sum [1024,64]     = 65536

// Workspace layout (float/int element offsets) — ~272 KB total (proven-safe envelope)
#define WS_IDX    0          // [0, 65536) int32
#define WS_LCPART 65536      // [65536, 66048) 512 floats
#define WS_COUNTS 66048      // [66048, 67072)
#define WS_CNORM  67072      // [67072, 68096)
#define WS_N      68096      // scalar

__global__ __launch_bounds__(64) void k_cnorm(const float* __restrict__ cb,
                                              float* __restrict__ cnorm) {
    int k = blockIdx.x * 64 + threadIdx.x;
    const float* c = cb + (size_t)k * DD;
    float s = 0.f;
#pragma unroll 8
    for (int j = 0; j < DD; ++j) s = fmaf(c[j], c[j], s);
    cnorm[k] = s;
}

// Fused: distance GEMM + argmin + e_k_ste/index writes + L_commit partial. No global atomics.
__global__ __launch_bounds__(256) void k_main(const float* __restrict__ z_e,
                                              const float* __restrict__ cb,
                                              const float* __restrict__ cnorm,
                                              float* __restrict__ out,
                                              int* __restrict__ idx_ws,
                                              float* __restrict__ lc_part) {
    __shared__ __align__(16) float At[64 * 128];   // z tile [j][i], live whole kernel
    __shared__ __align__(16) float Bt[64 * 68];    // codebook tile [j][k]; reused as reduce scratch
    __shared__ float zn[128];
    __shared__ int   idx_lds[128];
    __shared__ float lcred[4];

    const int t  = threadIdx.x;
    const int tx = t & 15;
    const int ty = t >> 4;
    const int n0 = blockIdx.x * 128;       // 512 blocks
    const int b   = n0 >> 12;
    const int hw0 = n0 & 4095;
    const float* zbase = z_e + (size_t)b * (DD * HW) + hw0;

#pragma unroll
    for (int s = 0; s < 8; ++s) {
        int idx = t + s * 256;              // 0..2047 float4s
        int j   = idx >> 5;
        int i4  = (idx & 31) << 2;
        float4 v = *(const float4*)(zbase + (size_t)j * HW + i4);
        *(float4*)(&At[j * 128 + i4]) = v;
    }
    __syncthreads();

    if (t < 128) {
        float s = 0.f;
        for (int j = 0; j < 64; ++j) { float a = At[j * 128 + t]; s = fmaf(a, a, s); }
        zn[t] = s;
    }
    __syncthreads();

    const int row0 = ty * 8, col0 = tx * 4;
    float znr[8];
#pragma unroll
    for (int r = 0; r < 8; ++r) znr[r] = zn[row0 + r];

    float mv[8]; int mi[8];
#pragma unroll
    for (int r = 0; r < 8; ++r) { mv[r] = 3.4e38f; mi[r] = 0; }

    for (int kt = 0; kt < 16; ++kt) {
        const int k0 = kt * 64;
        __syncthreads();
#pragma unroll
        for (int s = 0; s < 4; ++s) {
            int idx = t + s * 256;          // 0..1023 float4s
            int kk  = idx >> 4;
            int j4  = (idx & 15) << 2;
            float4 v = *(const float4*)(cb + (size_t)(k0 + kk) * DD + j4);
            Bt[(j4 + 0) * 68 + kk] = v.x;
            Bt[(j4 + 1) * 68 + kk] = v.y;
            Bt[(j4 + 2) * 68 + kk] = v.z;
            Bt[(j4 + 3) * 68 + kk] = v.w;
        }
        __syncthreads();

        float acc[8][4];
#pragma unroll
        for (int r = 0; r < 8; ++r)
#pragma unroll
            for (int c = 0; c < 4; ++c) acc[r][c] = 0.f;

#pragma unroll 8
        for (int j = 0; j < 64; ++j) {
            float4 a0 = *(const float4*)(&At[j * 128 + row0]);
            float4 a1 = *(const float4*)(&At[j * 128 + row0 + 4]);
            float4 bq = *(const float4*)(&Bt[j * 68 + col0]);
            float ar[8] = {a0.x, a0.y, a0.z, a0.w, a1.x, a1.y, a1.z, a1.w};
            float bc[4] = {bq.x, bq.y, bq.z, bq.w};
#pragma unroll
            for (int r = 0; r < 8; ++r)
#pragma unroll
                for (int c = 0; c < 4; ++c)
                    acc[r][c] = fmaf(ar[r], bc[c], acc[r][c]);
        }

#pragma unroll
        for (int c = 0; c < 4; ++c) {
            float cn = cnorm[k0 + col0 + c];
            int   kg = k0 + col0 + c;
#pragma unroll
            for (int r = 0; r < 8; ++r) {
                float v = (znr[r] - 2.0f * acc[r][c]) + cn;
                if (v < mv[r]) { mv[r] = v; mi[r] = kg; }   // kg ascending -> first-min
            }
        }
    }

    // ---- Argmin reduction in Bt scratch (At stays intact) ----
    __syncthreads();
    float* rv = Bt;                       // [128][17] floats
    int*   ri = (int*)(Bt + 2176);        // [128][17] ints
#pragma unroll
    for (int r = 0; r < 8; ++r) {
        rv[(row0 + r) * 17 + tx] = mv[r];
        ri[(row0 + r) * 17 + tx] = mi[r];
    }
    __syncthreads();
    if (t < 128) {
        float best = rv[t * 17 + 0];
        int   bi   = ri[t * 17 + 0];
#pragma unroll
        for (int c = 1; c < 16; ++c) {
            float v = rv[t * 17 + c];
            int   i = ri[t * 17 + c];
            if (v < best || (v == best && i < bi)) { best = v; bi = i; }
        }
        if ((unsigned)bi > 1023u) bi = 0;
        idx_lds[t] = bi;
        out[O_IDX + n0 + t] = (float)bi;
        idx_ws[n0 + t] = bi;
    }
    __syncthreads();

    // ---- e_k_ste + L_commit from LDS tile ----
    const int r   = t >> 1;
    const int j0  = (t & 1) * 32;
    int k = idx_lds[r];
    const float* ck = cb + (size_t)k * DD;
    const size_t obase = (size_t)b * (DD * HW) + (size_t)(hw0 + r);

    float lc = 0.f;
#pragma unroll 8
    for (int j = j0; j < j0 + 32; ++j) {
        float z = At[j * 128 + r];
        float e = ck[j];
        out[O_EK + obase + (size_t)j * HW] = z + (e - z);
        float d = z - e;
        lc = fmaf(d, d, lc);
    }
#pragma unroll
    for (int m = 32; m >= 1; m >>= 1) lc += __shfl_xor(lc, m, 64);
    if ((t & 63) == 0) lcred[t >> 6] = lc;
    __syncthreads();
    if (t == 0) lc_part[blockIdx.x] = lcred[0] + lcred[1] + lcred[2] + lcred[3];
}

// One block per feature j: coalesced scan of z[:,j,:], LDS-atomic accumulate per code.
__global__ __launch_bounds__(1024) void k_sums(const int* __restrict__ idx_ws,
                                               const float* __restrict__ z_e,
                                               const float* __restrict__ ema_sum,
                                               float* __restrict__ out) {
    __shared__ float acc[KC];
    const int j = blockIdx.x;          // 64 blocks
    const int t = threadIdx.x;         // 1024 threads
    acc[t] = 0.f;
    __syncthreads();
    const float* zj = z_e + (size_t)j * HW;
#pragma unroll 4
    for (int n = t; n < NTOT; n += 1024) {
        int b = n >> 12, hw = n & 4095;
        float z = zj[(size_t)b * (DD * HW) + hw];   // coalesced across lanes
        int   k = idx_ws[n];                        // L2-hot (256 KB)
        atomicAdd(&acc[k], z);                      // LDS atomic
    }
    __syncthreads();
    float ns = ema_sum[(size_t)t * DD + j] * 0.99f + 0.01f * acc[t];
    out[O_SUM + (size_t)t * DD + j] = ns;
}

// Histogram + new_count + n + L_commit (single block, LDS atomics)
__global__ __launch_bounds__(1024) void k_stats(const int* __restrict__ idx_ws,
                                                const float* __restrict__ ema_count,
                                                const float* __restrict__ lc_part,
                                                float* __restrict__ out,
                                                float* __restrict__ counts_ws,
                                                float* __restrict__ n_ws) {
    __shared__ int bins[KC];
    __shared__ float red[1024];
    const int t = threadIdx.x;
    bins[t] = 0;
    __syncthreads();
#pragma unroll 4
    for (int n = t; n < NTOT; n += 1024) atomicAdd(&bins[idx_ws[n]], 1);
    __syncthreads();
    float nc = ema_count[t] * 0.99f + 0.01f * (float)bins[t];
    out[O_CNT + t] = nc;
    counts_ws[t] = nc;
    red[t] = nc;
    __syncthreads();
    for (int s = 512; s >= 1; s >>= 1) { if (t < s) red[t] += red[t + s]; __syncthreads(); }
    if (t == 0) n_ws[0] = red[0];
    __syncthreads();
    red[t] = (t < 512) ? lc_part[t] : 0.f;
    __syncthreads();
    for (int s = 512; s >= 1; s >>= 1) { if (t < s) red[t] += red[t + s]; __syncthreads(); }
    if (t == 0) out[O_L] = 1.25f * red[0] * (1.0f / 4194304.0f);
}

// new_codebook = new_sum / count_s (reads new_sum back from out)
__global__ __launch_bounds__(256) void k_final_cb(const float* __restrict__ counts_ws,
                                                  const float* __restrict__ n_ws,
                                                  float* __restrict__ out) {
    const int e = blockIdx.x * 256 + threadIdx.x;   // 0..65535
    const int k = e >> 6;
    float ns = out[O_SUM + e];
    float nc = counts_ws[k];
    float n  = n_ws[0];
    float cs = (nc + 1e-5f) / (n + 1024.0f * 1e-5f) * n;
    out[O_CB + e] = ns / cs;
}

extern "C" void kernel_launch(void* const* d_in, const int* in_sizes, int n_in,
                              void* d_out, int out_size, void* d_ws, size_t ws_size,
                              hipStream_t stream) {
    const float* z_e       = (const float*)d_in[0];
    const float* cb        = (const float*)d_in[1];
    const float* ema_count = (const float*)d_in[2];
    const float* ema_sum   = (const float*)d_in[3];
    float* out             = (float*)d_out;

    float* ws_f      = (float*)d_ws;
    int*   idx_ws    = (int*)d_ws;
    float* lc_part   = ws_f + WS_LCPART;
    float* counts_ws = ws_f + WS_COUNTS;
    float* cnorm_ws  = ws_f + WS_CNORM;
    float* n_ws      = ws_f + WS_N;

    k_cnorm<<<KC / 64, 64, 0, stream>>>(cb, cnorm_ws);
    k_main<<<NTOT / 128, 256, 0, stream>>>(z_e, cb, cnorm_ws, out, idx_ws, lc_part);
    k_sums<<<DD, 1024, 0, stream>>>(idx_ws, z_e, ema_sum, out);
    k_stats<<<1, 1024, 0, stream>>>(idx_ws, ema_count, lc_part, out, counts_ws, n_ws);
    k_final_cb<<<NTOT / 256, 256, 0, stream>>>(counts_ws, n_ws, out);
}

// Round 7
// 233.146 us; speedup vs baseline: 4.3773x; 1.3046x over previous
//
#include <hip/hip_runtime.h>
#include <hip/hip_bf16.h>

// Problem constants
#define NB 16
#define DD 64
#define HW 4096          // 64*64
#define NTOT 65536       // NB*HW
#define KC 1024

// Output chunk offsets (FLOAT32 elements, return order)
#define O_EK   0                         // e_k_ste [16,64,64,64] = 4194304
#define O_IDX  4194304                   // indices [16,64,64]    = 65536
#define O_L    4259840                   // L_commit scalar       = 1
#define O_CB   4259841                   // new_codebook [1024,64]= 65536
#define O_CNT  4325377                   // new_count [1024]      = 1024
#define O_SUM  4326401                   // new_sum [1024,64]     = 65536

// Workspace layout (float/int element offsets) — ~1.39 MB total
#define WS_IDX    0          // [0, 65536) int32
#define WS_LCPART 65536      // 512 floats
#define WS_COUNTS 66048      // 1024
#define WS_CNORM  67072      // 1024
#define WS_N      68096      // scalar
#define WS_PSUM   68608      // 4 chunks x 65536 = 262144 -> ends 330752
#define WS_PCNT   330752     // 16 x 1024 ints -> ends 347136

// One wave per code: float4 loads + shuffle reduce (replaces latency-serial loop)
__global__ __launch_bounds__(256) void k_cnorm(const float* __restrict__ cb,
                                               float* __restrict__ cnorm) {
    const int w = (blockIdx.x * 256 + threadIdx.x) >> 6;   // code, 256 waves total... grid covers 1024
    const int l = threadIdx.x & 63;
    // 16 lanes used per code row: lane l<16 loads float4 l of the row
    float s = 0.f;
    if (l < 16) {
        float4 v = *(const float4*)(cb + (size_t)w * DD + l * 4);
        s = v.x * v.x + v.y * v.y + v.z * v.z + v.w * v.w;
    }
#pragma unroll
    for (int m = 1; m <= 8; m <<= 1) s += __shfl_xor(s, m, 64);
    if (l == 0) cnorm[w] = s;
}

// Fused: distance GEMM + argmin + e_k_ste/index writes + L_commit partial. No global atomics.
__global__ __launch_bounds__(256) void k_main(const float* __restrict__ z_e,
                                              const float* __restrict__ cb,
                                              const float* __restrict__ cnorm,
                                              float* __restrict__ out,
                                              int* __restrict__ idx_ws,
                                              float* __restrict__ lc_part) {
    __shared__ __align__(16) float At[64 * 128];   // z tile [j][i], live whole kernel (32 KB)
    __shared__ __align__(16) float Bt[4352];       // [j][k] stride 64 (4096 used); reduce scratch (4352)
    __shared__ float zn[128];
    __shared__ int   idx_lds[128];
    __shared__ float lcred[4];

    const int t  = threadIdx.x;
    const int tx = t & 15;
    const int ty = t >> 4;
    const int n0 = blockIdx.x * 128;       // 512 blocks
    const int b   = n0 >> 12;
    const int hw0 = n0 & 4095;
    const float* zbase = z_e + (size_t)b * (DD * HW) + hw0;

#pragma unroll
    for (int s = 0; s < 8; ++s) {
        int idx = t + s * 256;              // 0..2047 float4s
        int j   = idx >> 5;
        int i4  = (idx & 31) << 2;
        float4 v = *(const float4*)(zbase + (size_t)j * HW + i4);
        *(float4*)(&At[j * 128 + i4]) = v;
    }
    __syncthreads();

    if (t < 128) {
        float s = 0.f;
        for (int j = 0; j < 64; ++j) { float a = At[j * 128 + t]; s = fmaf(a, a, s); }
        zn[t] = s;
    }
    __syncthreads();

    const int row0 = ty * 8, col0 = tx * 4;
    float znr[8];
#pragma unroll
    for (int r = 0; r < 8; ++r) znr[r] = zn[row0 + r];

    float mv[8]; int mi[8];
#pragma unroll
    for (int r = 0; r < 8; ++r) { mv[r] = 3.4e38f; mi[r] = 0; }

    for (int kt = 0; kt < 16; ++kt) {
        const int k0 = kt * 64;
        __syncthreads();                    // protect Bt from previous readers
        // Staging remap: per item, kk = idx&63 (lane-consecutive), j-quad = idx>>6.
        // LDS stores hit consecutive banks (2-way, free). Global read is stride-256B
        // per lane but cb is 256 KB and L2-hot.
#pragma unroll
        for (int s = 0; s < 4; ++s) {
            int idx = t + s * 256;          // 0..1023
            int kk  = idx & 63;
            int j4  = (idx >> 6) << 2;      // 0,4,...,60
            float4 v = *(const float4*)(cb + (size_t)(k0 + kk) * DD + j4);
            Bt[(j4 + 0) * 64 + kk] = v.x;
            Bt[(j4 + 1) * 64 + kk] = v.y;
            Bt[(j4 + 2) * 64 + kk] = v.z;
            Bt[(j4 + 3) * 64 + kk] = v.w;
        }
        __syncthreads();

        float acc[8][4];
#pragma unroll
        for (int r = 0; r < 8; ++r)
#pragma unroll
            for (int c = 0; c < 4; ++c) acc[r][c] = 0.f;

#pragma unroll 8
        for (int j = 0; j < 64; ++j) {
            float4 a0 = *(const float4*)(&At[j * 128 + row0]);
            float4 a1 = *(const float4*)(&At[j * 128 + row0 + 4]);
            float4 bq = *(const float4*)(&Bt[j * 64 + col0]);
            float ar[8] = {a0.x, a0.y, a0.z, a0.w, a1.x, a1.y, a1.z, a1.w};
            float bc[4] = {bq.x, bq.y, bq.z, bq.w};
#pragma unroll
            for (int r = 0; r < 8; ++r)
#pragma unroll
                for (int c = 0; c < 4; ++c)
                    acc[r][c] = fmaf(ar[r], bc[c], acc[r][c]);
        }

#pragma unroll
        for (int c = 0; c < 4; ++c) {
            float cn = cnorm[k0 + col0 + c];
            int   kg = k0 + col0 + c;
#pragma unroll
            for (int r = 0; r < 8; ++r) {
                float v = (znr[r] - 2.0f * acc[r][c]) + cn;
                if (v < mv[r]) { mv[r] = v; mi[r] = kg; }   // kg ascending -> first-min
            }
        }
    }

    // ---- Argmin reduction in Bt scratch (At stays intact) ----
    __syncthreads();
    float* rv = Bt;                       // [128][17] floats = 2176
    int*   ri = (int*)(Bt + 2176);        // [128][17] ints   = 2176 (4352 total)
#pragma unroll
    for (int r = 0; r < 8; ++r) {
        rv[(row0 + r) * 17 + tx] = mv[r];
        ri[(row0 + r) * 17 + tx] = mi[r];
    }
    __syncthreads();
    if (t < 128) {
        float best = rv[t * 17 + 0];
        int   bi   = ri[t * 17 + 0];
#pragma unroll
        for (int c = 1; c < 16; ++c) {
            float v = rv[t * 17 + c];
            int   i = ri[t * 17 + c];
            if (v < best || (v == best && i < bi)) { best = v; bi = i; }
        }
        if ((unsigned)bi > 1023u) bi = 0;
        idx_lds[t] = bi;
        out[O_IDX + n0 + t] = (float)bi;
        idx_ws[n0 + t] = bi;
    }
    __syncthreads();

    // ---- e_k_ste + L_commit from LDS tile ----
    const int r   = t >> 1;
    const int j0  = (t & 1) * 32;
    int k = idx_lds[r];
    const float* ck = cb + (size_t)k * DD;
    const size_t obase = (size_t)b * (DD * HW) + (size_t)(hw0 + r);

    float lc = 0.f;
#pragma unroll 8
    for (int j = j0; j < j0 + 32; ++j) {
        float z = At[j * 128 + r];
        float e = ck[j];
        out[O_EK + obase + (size_t)j * HW] = z + (e - z);
        float d = z - e;
        lc = fmaf(d, d, lc);
    }
#pragma unroll
    for (int m = 32; m >= 1; m >>= 1) lc += __shfl_xor(lc, m, 64);
    if ((t & 63) == 0) lcred[t >> 6] = lc;
    __syncthreads();
    if (t == 0) lc_part[blockIdx.x] = lcred[0] + lcred[1] + lcred[2] + lcred[3];
}

// 256 blocks: (j, chunk c of 16384 n's). LDS accumulate, write partial psum[c][j][k].
__global__ __launch_bounds__(1024) void k_sums(const int* __restrict__ idx_ws,
                                               const float* __restrict__ z_e,
                                               float* __restrict__ psum) {
    __shared__ float acc[KC];
    const int j = blockIdx.x & 63;
    const int c = blockIdx.x >> 6;     // 0..3
    const int t = threadIdx.x;
    acc[t] = 0.f;
    __syncthreads();
    const float* zj = z_e + (size_t)j * HW;
    const int base = c * 16384;
#pragma unroll 4
    for (int i = 0; i < 16; ++i) {
        int n = base + i * 1024 + t;
        int b = n >> 12, hw = n & 4095;
        float z = zj[(size_t)b * (DD * HW) + hw];   // coalesced
        atomicAdd(&acc[idx_ws[n]], z);              // LDS atomic
    }
    __syncthreads();
    psum[(size_t)c * 65536 + j * 1024 + t] = acc[t];   // coalesced
}

// Reduce 4 partials + EMA -> new_sum
__global__ __launch_bounds__(1024) void k_sum_reduce(const float* __restrict__ psum,
                                                     const float* __restrict__ ema_sum,
                                                     float* __restrict__ out) {
    const int e = blockIdx.x * 1024 + threadIdx.x;  // 0..65535, e = j*1024 + k
    const int j = e >> 10, k = e & 1023;
    float s = psum[e] + psum[65536 + e] + psum[131072 + e] + psum[196608 + e];
    float ns = ema_sum[(size_t)k * DD + j] * 0.99f + 0.01f * s;
    out[O_SUM + (size_t)k * DD + j] = ns;           // scattered in 256 KB region; L2 absorbs
}

// 16 blocks: partial histograms of idx
__global__ __launch_bounds__(1024) void k_hist(const int* __restrict__ idx_ws,
                                               int* __restrict__ pcnt) {
    __shared__ int bins[KC];
    const int t = threadIdx.x;
    bins[t] = 0;
    __syncthreads();
    const int base = blockIdx.x * 4096;
#pragma unroll 4
    for (int i = 0; i < 4; ++i) atomicAdd(&bins[idx_ws[base + i * 1024 + t]], 1);
    __syncthreads();
    pcnt[blockIdx.x * 1024 + t] = bins[t];
}

// Reduce hist partials -> new_count, n; reduce lc_part -> L_commit
__global__ __launch_bounds__(1024) void k_stats(const int* __restrict__ pcnt,
                                                const float* __restrict__ ema_count,
                                                const float* __restrict__ lc_part,
                                                float* __restrict__ out,
                                                float* __restrict__ counts_ws,
                                                float* __restrict__ n_ws) {
    __shared__ float red[1024];
    const int t = threadIdx.x;
    int cnt = 0;
#pragma unroll
    for (int c = 0; c < 16; ++c) cnt += pcnt[c * 1024 + t];
    float nc = ema_count[t] * 0.99f + 0.01f * (float)cnt;
    out[O_CNT + t] = nc;
    counts_ws[t] = nc;
    red[t] = nc;
    __syncthreads();
    for (int s = 512; s >= 1; s >>= 1) { if (t < s) red[t] += red[t + s]; __syncthreads(); }
    if (t == 0) n_ws[0] = red[0];
    __syncthreads();
    red[t] = (t < 512) ? lc_part[t] : 0.f;
    __syncthreads();
    for (int s = 512; s >= 1; s >>= 1) { if (t < s) red[t] += red[t + s]; __syncthreads(); }
    if (t == 0) out[O_L] = 1.25f * red[0] * (1.0f / 4194304.0f);
}

// new_codebook = new_sum / count_s (reads new_sum back from out)
__global__ __launch_bounds__(256) void k_final_cb(const float* __restrict__ counts_ws,
                                                  const float* __restrict__ n_ws,
                                                  float* __restrict__ out) {
    const int e = blockIdx.x * 256 + threadIdx.x;   // 0..65535
    const int k = e >> 6;
    float ns = out[O_SUM + e];
    float nc = counts_ws[k];
    float n  = n_ws[0];
    float cs = (nc + 1e-5f) / (n + 1024.0f * 1e-5f) * n;
    out[O_CB + e] = ns / cs;
}

extern "C" void kernel_launch(void* const* d_in, const int* in_sizes, int n_in,
                              void* d_out, int out_size, void* d_ws, size_t ws_size,
                              hipStream_t stream) {
    const float* z_e       = (const float*)d_in[0];
    const float* cb        = (const float*)d_in[1];
    const float* ema_count = (const float*)d_in[2];
    const float* ema_sum   = (const float*)d_in[3];
    float* out             = (float*)d_out;

    float* ws_f      = (float*)d_ws;
    int*   idx_ws    = (int*)d_ws;
    float* lc_part   = ws_f + WS_LCPART;
    float* counts_ws = ws_f + WS_COUNTS;
    float* cnorm_ws  = ws_f + WS_CNORM;
    float* n_ws      = ws_f + WS_N;
    float* psum      = ws_f + WS_PSUM;
    int*   pcnt      = (int*)(ws_f + WS_PCNT);

    k_cnorm<<<KC / 4, 256, 0, stream>>>(cb, cnorm_ws);
    k_main<<<NTOT / 128, 256, 0, stream>>>(z_e, cb, cnorm_ws, out, idx_ws, lc_part);
    k_sums<<<256, 1024, 0, stream>>>(idx_ws, z_e, psum);
    k_hist<<<16, 1024, 0, stream>>>(idx_ws, pcnt);
    k_sum_reduce<<<64, 1024, 0, stream>>>(psum, ema_sum, out);
    k_stats<<<1, 1024, 0, stream>>>(pcnt, ema_count, lc_part, out, counts_ws, n_ws);
    k_final_cb<<<NTOT / 256, 256, 0, stream>>>(counts_ws, n_ws, out);
}

// Round 8
// 212.597 us; speedup vs baseline: 4.8004x; 1.0967x over previous
//
#include <hip/hip_runtime.h>
#include <hip/hip_bf16.h>

// Problem constants
#define NB 16
#define DD 64
#define HW 4096          // 64*64
#define NTOT 65536       // NB*HW
#define KC 1024

// Output chunk offsets (FLOAT32 elements, return order)
#define O_EK   0                         // e_k_ste [16,64,64,64] = 4194304
#define O_IDX  4194304                   // indices [16,64,64]    = 65536
#define O_L    4259840                   // L_commit scalar       = 1
#define O_CB   4259841                   // new_codebook [1024,64]= 65536
#define O_CNT  4325377                   // new_count [1024]      = 1024
#define O_SUM  4326401                   // new_sum [1024,64]     = 65536

// Workspace layout (float element offsets) — ~1.34 MB total
#define WS_IDX    0          // [0, 65536) int32
#define WS_LCPART 65536      // 512 floats
#define WS_N      66048      // scalar
#define WS_CNORM  66560      // 1024 (16B-aligned)
#define WS_PSUM   67584      // 4 x 65536 = 262144 -> ends 329728
#define WS_PCNT   329728     // 4 x 1024 ints -> ends 333824

// cnorm (one 16-lane wave-slice per code) + n = 0.99*sum(ema_count) + 0.01*N
__global__ __launch_bounds__(256) void k_pre(const float* __restrict__ cb,
                                             const float* __restrict__ ema_count,
                                             float* __restrict__ cnorm,
                                             float* __restrict__ n_ws) {
    const int t = threadIdx.x;
    const int w = (blockIdx.x * 256 + t) >> 6;   // code 0..1023 (grid 256)
    const int l = t & 63;
    float s = 0.f;
    if (l < 16) {
        float4 v = *(const float4*)(cb + (size_t)w * DD + l * 4);
        s = v.x * v.x + v.y * v.y + v.z * v.z + v.w * v.w;
    }
#pragma unroll
    for (int m = 1; m <= 8; m <<= 1) s += __shfl_xor(s, m, 64);
    if (l == 0) cnorm[w] = s;

    if (blockIdx.x == 0) {
        __shared__ float red[256];
        red[t] = ema_count[t] + ema_count[t + 256] + ema_count[t + 512] + ema_count[t + 768];
        __syncthreads();
        for (int s2 = 128; s2 >= 1; s2 >>= 1) {
            if (t < s2) red[t] += red[t + s2];
            __syncthreads();
        }
        if (t == 0) n_ws[0] = 0.99f * red[0] + 0.01f * 65536.0f;
    }
}

// Fused: distance GEMM (8x8 register tile) + argmin + e_k_ste/index + L_commit partial.
__global__ __launch_bounds__(256) void k_main(const float* __restrict__ z_e,
                                              const float* __restrict__ cb,
                                              const float* __restrict__ cnorm,
                                              float* __restrict__ out,
                                              int* __restrict__ idx_ws,
                                              float* __restrict__ lc_part) {
    __shared__ __align__(16) float At[64 * 128];   // z tile [j][i], live whole kernel (32 KB)
    __shared__ __align__(16) float Bt[64 * 128];   // codebook tile [j][k] (32 KB); reduce scratch
    __shared__ __align__(16) float cn_lds[KC];     // 4 KB
    __shared__ float zn[128];
    __shared__ int   idx_lds[128];
    __shared__ float lcred[4];

    const int t  = threadIdx.x;
    const int tx = t & 15;
    const int ty = t >> 4;
    const int n0 = blockIdx.x * 128;       // 512 blocks
    const int b   = n0 >> 12;
    const int hw0 = n0 & 4095;
    const float* zbase = z_e + (size_t)b * (DD * HW) + hw0;

    // ---- Load A tile (coalesced along hw) + cnorm to LDS ----
#pragma unroll
    for (int s = 0; s < 8; ++s) {
        int idx = t + s * 256;              // 0..2047 float4s
        int j   = idx >> 5;
        int i4  = (idx & 31) << 2;
        float4 v = *(const float4*)(zbase + (size_t)j * HW + i4);
        *(float4*)(&At[j * 128 + i4]) = v;
    }
    *(float4*)(&cn_lds[t * 4]) = *(const float4*)(cnorm + t * 4);
    __syncthreads();

    if (t < 128) {
        float s = 0.f;
        for (int j = 0; j < 64; ++j) { float a = At[j * 128 + t]; s = fmaf(a, a, s); }
        zn[t] = s;
    }
    __syncthreads();

    const int row0 = ty * 8, col0 = tx * 8;
    float znr[8];
#pragma unroll
    for (int r = 0; r < 8; ++r) znr[r] = zn[row0 + r];

    float mv[8]; int mi[8];
#pragma unroll
    for (int r = 0; r < 8; ++r) { mv[r] = 3.4e38f; mi[r] = 0; }

    for (int kt = 0; kt < 8; ++kt) {
        const int k0 = kt * 128;
        __syncthreads();                    // protect Bt from previous readers
        // Staging: kk lane-consecutive -> LDS stores conflict-free; global reads
        // stride-256B per lane but cb is 256 KB, L2-hot.
#pragma unroll
        for (int s = 0; s < 8; ++s) {
            int idx = t + s * 256;          // 0..2047
            int kk  = idx & 127;
            int jq  = (idx >> 7) << 2;      // 0,4,...,60
            float4 v = *(const float4*)(cb + (size_t)(k0 + kk) * DD + jq);
            Bt[(jq + 0) * 128 + kk] = v.x;
            Bt[(jq + 1) * 128 + kk] = v.y;
            Bt[(jq + 2) * 128 + kk] = v.z;
            Bt[(jq + 3) * 128 + kk] = v.w;
        }
        __syncthreads();

        float acc[8][8];
#pragma unroll
        for (int r = 0; r < 8; ++r)
#pragma unroll
            for (int c = 0; c < 8; ++c) acc[r][c] = 0.f;

#pragma unroll 8
        for (int j = 0; j < 64; ++j) {
            float4 a0 = *(const float4*)(&At[j * 128 + row0]);
            float4 a1 = *(const float4*)(&At[j * 128 + row0 + 4]);
            float4 b0 = *(const float4*)(&Bt[j * 128 + col0]);
            float4 b1 = *(const float4*)(&Bt[j * 128 + col0 + 4]);
            float ar[8] = {a0.x, a0.y, a0.z, a0.w, a1.x, a1.y, a1.z, a1.w};
            float bc[8] = {b0.x, b0.y, b0.z, b0.w, b1.x, b1.y, b1.z, b1.w};
#pragma unroll
            for (int r = 0; r < 8; ++r)
#pragma unroll
                for (int c = 0; c < 8; ++c)
                    acc[r][c] = fmaf(ar[r], bc[c], acc[r][c]);
        }

#pragma unroll
        for (int c = 0; c < 8; ++c) {
            float cn = cn_lds[k0 + col0 + c];
            int   kg = k0 + col0 + c;
#pragma unroll
            for (int r = 0; r < 8; ++r) {
                float v = (znr[r] - 2.0f * acc[r][c]) + cn;
                if (v < mv[r]) { mv[r] = v; mi[r] = kg; }   // kg ascending -> first-min
            }
        }
    }

    // ---- Argmin reduction in Bt scratch (At stays intact) ----
    __syncthreads();
    float* rv = Bt;                       // [128][17] floats = 2176
    int*   ri = (int*)(Bt + 2176);        // [128][17] ints   = 2176 (Bt has 8192)
#pragma unroll
    for (int r = 0; r < 8; ++r) {
        rv[(row0 + r) * 17 + tx] = mv[r];
        ri[(row0 + r) * 17 + tx] = mi[r];
    }
    __syncthreads();
    if (t < 128) {
        float best = rv[t * 17 + 0];
        int   bi   = ri[t * 17 + 0];
#pragma unroll
        for (int c = 1; c < 16; ++c) {
            float v = rv[t * 17 + c];
            int   i = ri[t * 17 + c];
            if (v < best || (v == best && i < bi)) { best = v; bi = i; }
        }
        if ((unsigned)bi > 1023u) bi = 0;
        idx_lds[t] = bi;
        out[O_IDX + n0 + t] = (float)bi;
        idx_ws[n0 + t] = bi;
    }
    __syncthreads();

    // ---- e_k_ste + L_commit from LDS tile ----
    const int r   = t >> 1;
    const int j0  = (t & 1) * 32;
    int k = idx_lds[r];
    const float* ck = cb + (size_t)k * DD;
    const size_t obase = (size_t)b * (DD * HW) + (size_t)(hw0 + r);

    float lc = 0.f;
#pragma unroll 8
    for (int j = j0; j < j0 + 32; ++j) {
        float z = At[j * 128 + r];
        float e = ck[j];
        out[O_EK + obase + (size_t)j * HW] = z + (e - z);
        float d = z - e;
        lc = fmaf(d, d, lc);
    }
#pragma unroll
    for (int m = 32; m >= 1; m >>= 1) lc += __shfl_xor(lc, m, 64);
    if ((t & 63) == 0) lcred[t >> 6] = lc;
    __syncthreads();
    if (t == 0) lc_part[blockIdx.x] = lcred[0] + lcred[1] + lcred[2] + lcred[3];
}

// 256 blocks: (j, chunk c). LDS accumulate z per code; j==0 blocks also histogram.
__global__ __launch_bounds__(1024) void k_sums(const int* __restrict__ idx_ws,
                                               const float* __restrict__ z_e,
                                               float* __restrict__ psum,
                                               int* __restrict__ pcnt) {
    __shared__ float acc[KC];
    __shared__ int bins[KC];
    const int j = blockIdx.x & 63;
    const int c = blockIdx.x >> 6;     // 0..3
    const int t = threadIdx.x;
    acc[t] = 0.f;
    bins[t] = 0;
    __syncthreads();
    const float* zj = z_e + (size_t)j * HW;
    const int base = c * 16384;
    if (j == 0) {
#pragma unroll 4
        for (int i = 0; i < 16; ++i) {
            int n = base + i * 1024 + t;
            int b = n >> 12, hw = n & 4095;
            float z = zj[(size_t)b * (DD * HW) + hw];
            int   k = idx_ws[n];
            atomicAdd(&acc[k], z);
            atomicAdd(&bins[k], 1);
        }
    } else {
#pragma unroll 4
        for (int i = 0; i < 16; ++i) {
            int n = base + i * 1024 + t;
            int b = n >> 12, hw = n & 4095;
            float z = zj[(size_t)b * (DD * HW) + hw];
            atomicAdd(&acc[idx_ws[n]], z);
        }
    }
    __syncthreads();
    psum[(size_t)c * 65536 + j * 1024 + t] = acc[t];
    if (j == 0) pcnt[c * 1024 + t] = bins[t];
}

// Fused epilogue: new_sum, new_count, new_codebook, L_commit. 64 blocks (j) x 1024 (k).
__global__ __launch_bounds__(1024) void k_epi(const float* __restrict__ psum,
                                              const int* __restrict__ pcnt,
                                              const float* __restrict__ ema_sum,
                                              const float* __restrict__ ema_count,
                                              const float* __restrict__ n_ws,
                                              const float* __restrict__ lc_part,
                                              float* __restrict__ out) {
    const int j = blockIdx.x, t = threadIdx.x;   // t = k
    const int e = j * 1024 + t;
    float s4 = psum[e] + psum[65536 + e] + psum[131072 + e] + psum[196608 + e];
    float ns = ema_sum[(size_t)t * DD + j] * 0.99f + 0.01f * s4;
    out[O_SUM + (size_t)t * DD + j] = ns;
    int cnt = pcnt[t] + pcnt[1024 + t] + pcnt[2048 + t] + pcnt[3072 + t];
    float nc = ema_count[t] * 0.99f + 0.01f * (float)cnt;
    float n  = n_ws[0];
    float cs = (nc + 1e-5f) / (n + 1024.0f * 1e-5f) * n;
    out[O_CB + (size_t)t * DD + j] = ns / cs;
    if (j == 0) {
        out[O_CNT + t] = nc;
        __shared__ float red[512];
        if (t < 512) red[t] = lc_part[t];
        __syncthreads();
        for (int s = 256; s >= 1; s >>= 1) {
            if (t < s) red[t] += red[t + s];
            __syncthreads();
        }
        if (t == 0) out[O_L] = 1.25f * red[0] * (1.0f / 4194304.0f);
    }
}

extern "C" void kernel_launch(void* const* d_in, const int* in_sizes, int n_in,
                              void* d_out, int out_size, void* d_ws, size_t ws_size,
                              hipStream_t stream) {
    const float* z_e       = (const float*)d_in[0];
    const float* cb        = (const float*)d_in[1];
    const float* ema_count = (const float*)d_in[2];
    const float* ema_sum   = (const float*)d_in[3];
    float* out             = (float*)d_out;

    float* ws_f      = (float*)d_ws;
    int*   idx_ws    = (int*)d_ws;
    float* lc_part   = ws_f + WS_LCPART;
    float* n_ws      = ws_f + WS_N;
    float* cnorm_ws  = ws_f + WS_CNORM;
    float* psum      = ws_f + WS_PSUM;
    int*   pcnt      = (int*)(ws_f + WS_PCNT);

    k_pre<<<256, 256, 0, stream>>>(cb, ema_count, cnorm_ws, n_ws);
    k_main<<<NTOT / 128, 256, 0, stream>>>(z_e, cb, cnorm_ws, out, idx_ws, lc_part);
    k_sums<<<256, 1024, 0, stream>>>(idx_ws, z_e, psum, pcnt);
    k_epi<<<64, 1024, 0, stream>>>(psum, pcnt, ema_sum, ema_count, n_ws, lc_part, out);
}